// Round 11
// baseline (89.132 us; speedup 1.0000x reference)
//
#include <hip/hip_runtime.h>

#define KK 40        // N_RADIAL * N_ANGULAR
#define M3 120       // KK * 3
#define MM4 30       // float4 chunks of bw/bi per vertex
#define RCH 15       // chunks per staging round
#define FEAT 16
#define NT 8
#define ODIM 32
#define VPB 64       // vertices per block
#define BLOCK 512
#define SST 17       // staged stream row stride (float4 units) — bank-spread

typedef unsigned int u32;
typedef unsigned short u16;
typedef float  f32x2 __attribute__((ext_vector_type(2)));
typedef float  f32x4 __attribute__((ext_vector_type(4)));
typedef int    i32x4 __attribute__((ext_vector_type(4)));
typedef u32    u32x4 __attribute__((ext_vector_type(4)));

__device__ __forceinline__ u16 f2bf_rne(float x) {
    u32 u = __float_as_uint(x);
    u32 r = (u + 0x7fffu + ((u >> 16) & 1u)) >> 16;   // round-to-nearest-even
    return (u16)r;
}

// fused prep: block 0 computes cs3; remaining blocks convert mesh fp32->bf16
__global__ void prep_kernel(const float* __restrict__ mesh, const float* __restrict__ ic,
                            u16* __restrict__ mbf, float* __restrict__ cs3, int total) {
    const int t = threadIdx.x;
    if (blockIdx.x == 0) {
        __shared__ float cs[KK];
        if (t < KK) {
            float s = 0.f;
            #pragma unroll
            for (int ra = 0; ra < KK; ++ra) s += ic[ra * KK + t];
            cs[t] = s;
        }
        __syncthreads();
        if (t < M3) cs3[t] = cs[t / 3];
        return;
    }
    const int i = (blockIdx.x - 1) * BLOCK + t;
    const int base = i * 8;
    if (base < total) {
        f32x4 a = __builtin_nontemporal_load((const f32x4*)(mesh + base));
        f32x4 b = __builtin_nontemporal_load((const f32x4*)(mesh + base + 4));
        u32x4 v;
        v.x = (u32)f2bf_rne(a.x) | ((u32)f2bf_rne(a.y) << 16);
        v.y = (u32)f2bf_rne(a.z) | ((u32)f2bf_rne(a.w) << 16);
        v.z = (u32)f2bf_rne(b.x) | ((u32)f2bf_rne(b.y) << 16);
        v.w = (u32)f2bf_rne(b.z) | ((u32)f2bf_rne(b.w) << 16);
        *(u32x4*)(mbf + base) = v;   // normal store: leave bf16 mesh warm in L2
    }
}

// accumulate one gathered bf16x8 row-half (u32x4) scaled by s into acc2[0..3]
__device__ __forceinline__ void acc8(f32x2 acc2[4], const u32x4 g, const float s) {
    const f32x2 s2 = {s, s};
    f32x2 p;
    p.x = __uint_as_float(g.x << 16);
    p.y = __uint_as_float(g.x & 0xffff0000u);
    acc2[0] = __builtin_elementwise_fma(p, s2, acc2[0]);
    p.x = __uint_as_float(g.y << 16);
    p.y = __uint_as_float(g.y & 0xffff0000u);
    acc2[1] = __builtin_elementwise_fma(p, s2, acc2[1]);
    p.x = __uint_as_float(g.z << 16);
    p.y = __uint_as_float(g.z & 0xffff0000u);
    acc2[2] = __builtin_elementwise_fma(p, s2, acc2[2]);
    p.x = __uint_as_float(g.w << 16);
    p.y = __uint_as_float(g.w & 0xffff0000u);
    acc2[3] = __builtin_elementwise_fma(p, s2, acc2[3]);
}

// issue 4 L1-bypassing (sc0) 16B gathers, NO wait — caller waits with counted vmcnt
__device__ __forceinline__ void issue4_sc0(const u32x4* p0, const u32x4* p1,
                                           const u32x4* p2, const u32x4* p3,
                                           u32x4& g0, u32x4& g1, u32x4& g2, u32x4& g3) {
    asm volatile(
        "global_load_dwordx4 %0, %4, off sc0\n\t"
        "global_load_dwordx4 %1, %5, off sc0\n\t"
        "global_load_dwordx4 %2, %6, off sc0\n\t"
        "global_load_dwordx4 %3, %7, off sc0"
        : "=&v"(g0), "=&v"(g1), "=&v"(g2), "=&v"(g3)
        : "v"(p0), "v"(p1), "v"(p2), "v"(p3)
        : "memory");
}

#define WAIT_VM4() do { asm volatile("s_waitcnt vmcnt(4)" ::: "memory"); \
                        __builtin_amdgcn_sched_barrier(0); } while (0)
#define WAIT_VM0() do { asm volatile("s_waitcnt vmcnt(0)" ::: "memory"); \
                        __builtin_amdgcn_sched_barrier(0); } while (0)

struct GBatch { u32x4 g0, g1, g2, g3; float w0, w1, w2, w3; };

// prep batch b (chunk slots 2b, 2b+1): select weights/indices from LDS, issue 4 gathers
__device__ __forceinline__ void prep_issue(GBatch& B,
                                           const f32x4* __restrict__ s_bw4,
                                           const i32x4* __restrict__ s_bi4,
                                           int row, int cbase, int jc, int q, int mc, int b,
                                           const u16* __restrict__ mbf) {
    const int s0 = 2 * b, s1 = 2 * b + 1;
    const bool v0 = (mc == 0) || (s0 < 7);
    const bool v1 = (mc == 0) || (s1 < 7);
    const f32x4 wq0 = s_bw4[row + cbase + (v0 ? s0 : 0)];
    const i32x4 iq0 = s_bi4[row + cbase + (v0 ? s0 : 0)];
    const f32x4 wq1 = s_bw4[row + cbase + (v1 ? s1 : 0)];
    const i32x4 iq1 = s_bi4[row + cbase + (v1 ? s1 : 0)];
    B.w0 = v0 ? (jc ? wq0.z : wq0.x) : 0.f;
    B.w1 = v0 ? (jc ? wq0.w : wq0.y) : 0.f;
    B.w2 = v1 ? (jc ? wq1.z : wq1.x) : 0.f;
    B.w3 = v1 ? (jc ? wq1.w : wq1.y) : 0.f;
    const int i0 = v0 ? (jc ? iq0.z : iq0.x) : 0;
    const int i1 = v0 ? (jc ? iq0.w : iq0.y) : 0;
    const int i2 = v1 ? (jc ? iq1.z : iq1.x) : 0;
    const int i3 = v1 ? (jc ? iq1.w : iq1.y) : 0;
    issue4_sc0((const u32x4*)(mbf + (size_t)i0 * FEAT) + q,
               (const u32x4*)(mbf + (size_t)i1 * FEAT) + q,
               (const u32x4*)(mbf + (size_t)i2 * FEAT) + q,
               (const u32x4*)(mbf + (size_t)i3 * FEAT) + q,
               B.g0, B.g1, B.g2, B.g3);
}

__device__ __forceinline__ void consume(f32x2 acc2[4], const GBatch& B) {
    acc8(acc2, B.g0, B.w0);
    acc8(acc2, B.g1, B.w1);
    acc8(acc2, B.g2, B.w2);
    acc8(acc2, B.g3, B.w3);
}

__global__ __launch_bounds__(BLOCK, 6) void conv_kernel(
    const u16*   __restrict__ mbf,    // [N,16] bf16, L2-resident (3.2 MB)
    const float* __restrict__ bw,     // [N,120]
    const float* __restrict__ W,      // [8,32,16]
    const float* __restrict__ bias,   // [8,32]
    const int*   __restrict__ bi,     // [N,120]
    const float* __restrict__ cs3,    // [120]
    float*       __restrict__ out,    // [N,32]
    int n)
{
    // stream staging buffer (bw | bi), reused as s_out in phase 2/3
    __shared__ f32x4 s_buf[VPB * SST * 2];               // 34816 B
    __shared__ float s_sig[VPB][FEAT + 1];               //  4352 B

    f32x4* s_bw4 = s_buf;
    i32x4* s_bi4 = (i32x4*)(s_buf + VPB * SST);
    float (*s_out)[ODIM + 1] = (float(*)[ODIM + 1])s_buf;

    const int tid = threadIdx.x;
    const int vg0 = blockIdx.x * VPB;

    const f32x4* bw4g  = (const f32x4*)bw;
    const i32x4* bi4g  = (const i32x4*)bi;
    const f32x4* cs34g = (const f32x4*)cs3;

    // phase-1 lane mapping: tid = vloc*8 + jc*4 + mc*2 + q
    const int vloc = tid >> 3;
    const int jc   = (tid >> 2) & 1;
    const int mc   = (tid >> 1) & 1;
    const int q    = tid & 1;
    const int vg   = vg0 + vloc;

    f32x2 acc2[4];
    #pragma unroll
    for (int e = 0; e < 4; ++e) acc2[e] = (f32x2){0.f, 0.f};

    #pragma unroll
    for (int r = 0; r < 2; ++r) {
        if (r) __syncthreads();   // round-0 LDS reads done before restaging

        // ---- cooperative staging: each stream byte loaded exactly once ----
        // 960 chunk-slots, 512 threads -> 2 iterations
        #pragma unroll
        for (int ii = 0; ii < 2; ++ii) {
            const int i = tid + ii * BLOCK;
            if (i < VPB * RCH) {
                const int v = i / RCH;
                const int c = i - v * RCH;
                if (vg0 + v < n) {
                    const int gchunk = (vg0 + v) * MM4 + r * RCH + c;
                    f32x4 wv = __builtin_nontemporal_load(bw4g + gchunk);
                    i32x4 iv = __builtin_nontemporal_load(bi4g + gchunk);
                    const f32x4 cc = cs34g[r * RCH + c];
                    wv.x *= cc.x; wv.y *= cc.y; wv.z *= cc.z; wv.w *= cc.w;
                    s_bw4[v * SST + c] = wv;
                    s_bi4[v * SST + c] = iv;
                }
            }
        }
        __syncthreads();

        // ---- gather round r: 16 gathers/lane, depth-2 pipelined (8 in flight),
        //      counted vmcnt(4) so batch b+1's latency hides under consume(b).
        if (vg < n) {
            const int row   = vloc * SST;
            const int cbase = mc ? 8 : 0;
            GBatch A, B, C, D;
            prep_issue(A, s_bw4, s_bi4, row, cbase, jc, q, mc, 0, mbf);
            prep_issue(B, s_bw4, s_bi4, row, cbase, jc, q, mc, 1, mbf);
            WAIT_VM4();
            consume(acc2, A);
            prep_issue(C, s_bw4, s_bi4, row, cbase, jc, q, mc, 2, mbf);
            WAIT_VM4();
            consume(acc2, B);
            prep_issue(D, s_bw4, s_bi4, row, cbase, jc, q, mc, 3, mbf);
            WAIT_VM4();
            consume(acc2, C);
            WAIT_VM0();
            consume(acc2, D);
        }
    }

    // ---- cross-lane reduce: jc (xor 4) then mc (xor 2) ----
    float a8[8] = { acc2[0].x, acc2[0].y, acc2[1].x, acc2[1].y,
                    acc2[2].x, acc2[2].y, acc2[3].x, acc2[3].y };
    #pragma unroll
    for (int e = 0; e < 8; ++e) a8[e] += __shfl_xor(a8[e], 4);
    #pragma unroll
    for (int e = 0; e < 8; ++e) a8[e] += __shfl_xor(a8[e], 2);

    if (jc == 0) {
        const f32x4 v = (mc == 0) ? (f32x4){a8[0], a8[1], a8[2], a8[3]}
                                  : (f32x4){a8[4], a8[5], a8[6], a8[7]};
        *(f32x4*)(&s_sig[vloc][q * 8 + mc * 4]) = v;
    }
    __syncthreads();   // s_sig ready; stream reads all done (s_buf reusable)

    // ---------------- Phase 2: fold (W @ s, relu, sum over t) ----------------
    // wave w (0..7) owns wave-uniform outputs [4w, 4w+4); lane = vertex (64).
    // Output pairs accumulated as f32x2 -> v_pk_fma_f32 (half the instrs).
    {
        const int lane = tid & 63;
        const int wave = __builtin_amdgcn_readfirstlane(tid >> 6);  // 0..7

        float s[FEAT];
        #pragma unroll
        for (int f = 0; f < FEAT; ++f) s[f] = s_sig[lane][f];

        f32x2 oacc[2];
        oacc[0] = (f32x2){0.f, 0.f};
        oacc[1] = (f32x2){0.f, 0.f};
        const f32x2 zero2 = {0.f, 0.f};

        #pragma unroll 2
        for (int t = 0; t < NT; ++t) {
            #pragma unroll
            for (int op = 0; op < 2; ++op) {
                const int o0 = wave * 4 + op * 2;
                f32x2 pre = { bias[t * ODIM + o0], bias[t * ODIM + o0 + 1] };  // scalar
                const float* w0 = W + ((size_t)t * ODIM + o0) * FEAT;          // scalar
                const float* w1 = w0 + FEAT;
                #pragma unroll
                for (int f = 0; f < FEAT; ++f) {
                    const f32x2 wp = { w0[f], w1[f] };
                    const f32x2 sp = { s[f], s[f] };
                    pre = __builtin_elementwise_fma(wp, sp, pre);
                }
                oacc[op] += __builtin_elementwise_max(pre, zero2);
            }
        }

        *(f32x4*)(&s_out[lane][wave * 4]) =
            (f32x4){oacc[0].x, oacc[0].y, oacc[1].x, oacc[1].y};
    }
    __syncthreads();

    // ---------------- Phase 3: coalesced output write (normal stores) --------
    // 8 threads per vertex; each writes one float4 -> full 128B line/vertex.
    {
        const int v   = tid >> 3;
        const int oq  = tid & 7;
        const int vgo = vg0 + v;
        if (vgo < n) {
            const f32x4 val = { s_out[v][oq * 4 + 0], s_out[v][oq * 4 + 1],
                                s_out[v][oq * 4 + 2], s_out[v][oq * 4 + 3] };
            *(f32x4*)(out + (size_t)vgo * ODIM + oq * 4) = val;
        }
    }
}

extern "C" void kernel_launch(void* const* d_in, const int* in_sizes, int n_in,
                              void* d_out, int out_size, void* d_ws, size_t ws_size,
                              hipStream_t stream) {
    const float* mesh = (const float*)d_in[0];
    const float* bw   = (const float*)d_in[1];
    const float* ic   = (const float*)d_in[2];
    const float* W    = (const float*)d_in[3];
    const float* bias = (const float*)d_in[4];
    const int*   bi   = (const int*)d_in[5];
    float* out = (float*)d_out;

    const int n = in_sizes[0] / FEAT;   // N_VERTS
    const int total = n * FEAT;

    // workspace layout: [0,512) cs3, [512, 512 + n*16*2) bf16 mesh
    float* cs3 = (float*)d_ws;
    u16*   mbf = (u16*)((char*)d_ws + 512);

    const int cvt_blocks = (total / 8 + BLOCK - 1) / BLOCK;
    prep_kernel<<<cvt_blocks + 1, BLOCK, 0, stream>>>(mesh, ic, mbf, cs3, total);

    const int blocks = (n + VPB - 1) / VPB;
    conv_kernel<<<blocks, BLOCK, 0, stream>>>(mbf, bw, W, bias, bi, cs3, out, n);
}

// Round 12
// 85.578 us; speedup vs baseline: 1.0415x; 1.0415x over previous
//
#include <hip/hip_runtime.h>

#define KK 40        // N_RADIAL * N_ANGULAR
#define M3 120       // KK * 3
#define MM4 30       // float4 chunks of bw/bi per vertex
#define FEAT 16
#define NT 8
#define ODIM 32
#define VPB 64       // vertices per block
#define BLOCK 512
#define SST 31       // staged row stride (f32x4 units), odd -> all 8 bank-groups

typedef unsigned int u32;
typedef unsigned short u16;
typedef float  f32x2 __attribute__((ext_vector_type(2)));
typedef float  f32x4 __attribute__((ext_vector_type(4)));
typedef int    i32x4 __attribute__((ext_vector_type(4)));
typedef u32    u32x4 __attribute__((ext_vector_type(4)));

__device__ __forceinline__ u16 f2bf_rne(float x) {
    u32 u = __float_as_uint(x);
    u32 r = (u + 0x7fffu + ((u >> 16) & 1u)) >> 16;   // round-to-nearest-even
    return (u16)r;
}

// fused prep: block 0 computes cs3; remaining blocks convert mesh fp32->bf16
__global__ void prep_kernel(const float* __restrict__ mesh, const float* __restrict__ ic,
                            u16* __restrict__ mbf, float* __restrict__ cs3, int total) {
    const int t = threadIdx.x;
    if (blockIdx.x == 0) {
        __shared__ float cs[KK];
        if (t < KK) {
            float s = 0.f;
            #pragma unroll
            for (int ra = 0; ra < KK; ++ra) s += ic[ra * KK + t];
            cs[t] = s;
        }
        __syncthreads();
        if (t < M3) cs3[t] = cs[t / 3];
        return;
    }
    const int i = (blockIdx.x - 1) * BLOCK + t;
    const int base = i * 8;
    if (base < total) {
        f32x4 a = __builtin_nontemporal_load((const f32x4*)(mesh + base));
        f32x4 b = __builtin_nontemporal_load((const f32x4*)(mesh + base + 4));
        u32x4 v;
        v.x = (u32)f2bf_rne(a.x) | ((u32)f2bf_rne(a.y) << 16);
        v.y = (u32)f2bf_rne(a.z) | ((u32)f2bf_rne(a.w) << 16);
        v.z = (u32)f2bf_rne(b.x) | ((u32)f2bf_rne(b.y) << 16);
        v.w = (u32)f2bf_rne(b.z) | ((u32)f2bf_rne(b.w) << 16);
        *(u32x4*)(mbf + base) = v;   // normal store: leave bf16 mesh warm in L2
    }
}

// accumulate one gathered bf16x8 row-half (u32x4) scaled by s into acc2[0..3]
__device__ __forceinline__ void acc8(f32x2 acc2[4], const u32x4 g, const float s) {
    const f32x2 s2 = {s, s};
    f32x2 p;
    p.x = __uint_as_float(g.x << 16);
    p.y = __uint_as_float(g.x & 0xffff0000u);
    acc2[0] = __builtin_elementwise_fma(p, s2, acc2[0]);
    p.x = __uint_as_float(g.y << 16);
    p.y = __uint_as_float(g.y & 0xffff0000u);
    acc2[1] = __builtin_elementwise_fma(p, s2, acc2[1]);
    p.x = __uint_as_float(g.z << 16);
    p.y = __uint_as_float(g.z & 0xffff0000u);
    acc2[2] = __builtin_elementwise_fma(p, s2, acc2[2]);
    p.x = __uint_as_float(g.w << 16);
    p.y = __uint_as_float(g.w & 0xffff0000u);
    acc2[3] = __builtin_elementwise_fma(p, s2, acc2[3]);
}

// issue 6 L1-bypassing (sc0) 16B gathers, NO wait — caller uses counted vmcnt
__device__ __forceinline__ void issue6_sc0(const u32x4* p0, const u32x4* p1,
                                           const u32x4* p2, const u32x4* p3,
                                           const u32x4* p4, const u32x4* p5,
                                           u32x4& g0, u32x4& g1, u32x4& g2,
                                           u32x4& g3, u32x4& g4, u32x4& g5) {
    asm volatile(
        "global_load_dwordx4 %0, %6, off sc0\n\t"
        "global_load_dwordx4 %1, %7, off sc0\n\t"
        "global_load_dwordx4 %2, %8, off sc0\n\t"
        "global_load_dwordx4 %3, %9, off sc0\n\t"
        "global_load_dwordx4 %4, %10, off sc0\n\t"
        "global_load_dwordx4 %5, %11, off sc0"
        : "=&v"(g0), "=&v"(g1), "=&v"(g2), "=&v"(g3), "=&v"(g4), "=&v"(g5)
        : "v"(p0), "v"(p1), "v"(p2), "v"(p3), "v"(p4), "v"(p5)
        : "memory");
}

#define WAIT_VM6() do { asm volatile("s_waitcnt vmcnt(6)" ::: "memory"); \
                        __builtin_amdgcn_sched_barrier(0); } while (0)
#define WAIT_VM0() do { asm volatile("s_waitcnt vmcnt(0)" ::: "memory"); \
                        __builtin_amdgcn_sched_barrier(0); } while (0)

struct GB6 { u32x4 g0, g1, g2, g3, g4, g5; float w0, w1, w2, w3, w4, w5; };

// prep batch (3 chunks at cbeg..cbeg+2): LDS-read weights/indices, issue 6 gathers
__device__ __forceinline__ void prep3(GB6& B,
                                      const f32x4* __restrict__ s_bw4,
                                      const i32x4* __restrict__ s_bi4,
                                      int row, int cbeg, int jc, int q,
                                      const u16* __restrict__ mbf) {
    const f32x4 wqa = s_bw4[row + cbeg + 0];
    const i32x4 iqa = s_bi4[row + cbeg + 0];
    const f32x4 wqb = s_bw4[row + cbeg + 1];
    const i32x4 iqb = s_bi4[row + cbeg + 1];
    const f32x4 wqc = s_bw4[row + cbeg + 2];
    const i32x4 iqc = s_bi4[row + cbeg + 2];
    B.w0 = jc ? wqa.z : wqa.x;  B.w1 = jc ? wqa.w : wqa.y;
    B.w2 = jc ? wqb.z : wqb.x;  B.w3 = jc ? wqb.w : wqb.y;
    B.w4 = jc ? wqc.z : wqc.x;  B.w5 = jc ? wqc.w : wqc.y;
    const int i0 = jc ? iqa.z : iqa.x;
    const int i1 = jc ? iqa.w : iqa.y;
    const int i2 = jc ? iqb.z : iqb.x;
    const int i3 = jc ? iqb.w : iqb.y;
    const int i4 = jc ? iqc.z : iqc.x;
    const int i5 = jc ? iqc.w : iqc.y;
    issue6_sc0((const u32x4*)(mbf + (size_t)i0 * FEAT) + q,
               (const u32x4*)(mbf + (size_t)i1 * FEAT) + q,
               (const u32x4*)(mbf + (size_t)i2 * FEAT) + q,
               (const u32x4*)(mbf + (size_t)i3 * FEAT) + q,
               (const u32x4*)(mbf + (size_t)i4 * FEAT) + q,
               (const u32x4*)(mbf + (size_t)i5 * FEAT) + q,
               B.g0, B.g1, B.g2, B.g3, B.g4, B.g5);
}

__device__ __forceinline__ void consume6(f32x2 acc2[4], const GB6& B) {
    acc8(acc2, B.g0, B.w0);
    acc8(acc2, B.g1, B.w1);
    acc8(acc2, B.g2, B.w2);
    acc8(acc2, B.g3, B.w3);
    acc8(acc2, B.g4, B.w4);
    acc8(acc2, B.g5, B.w5);
}

__global__ __launch_bounds__(BLOCK, 4) void conv_kernel(
    const u16*   __restrict__ mbf,    // [N,16] bf16, L2-resident (3.2 MB)
    const float* __restrict__ bw,     // [N,120]
    const float* __restrict__ W,      // [8,32,16]
    const float* __restrict__ bias,   // [8,32]
    const int*   __restrict__ bi,     // [N,120]
    const float* __restrict__ cs3,    // [120]
    float*       __restrict__ out,    // [N,32]
    int n)
{
    // full-tile stream staging (bw | bi), reused as s_out in phase 2/3
    __shared__ f32x4 s_buf[VPB * SST * 2];               // 63488 B
    __shared__ float s_sig[VPB][FEAT + 1];               //  4352 B

    f32x4* s_bw4 = s_buf;
    i32x4* s_bi4 = (i32x4*)(s_buf + VPB * SST);
    float (*s_out)[ODIM + 1] = (float(*)[ODIM + 1])s_buf;

    const int tid = threadIdx.x;
    const int vg0 = blockIdx.x * VPB;

    const f32x4* bw4g  = (const f32x4*)bw;
    const i32x4* bi4g  = (const i32x4*)bi;
    const f32x4* cs34g = (const f32x4*)cs3;

    // phase-1 lane mapping: tid = vloc*8 + jc*4 + mc*2 + q
    const int vloc = tid >> 3;
    const int jc   = (tid >> 2) & 1;
    const int mc   = (tid >> 1) & 1;
    const int q    = tid & 1;
    const int vg   = vg0 + vloc;

    // ---- single-round cooperative staging: every stream byte loaded once ----
    // 1920 chunk-slots, 512 threads -> 4 iterations
    #pragma unroll
    for (int ii = 0; ii < 4; ++ii) {
        const int i = tid + ii * BLOCK;
        if (i < VPB * MM4) {
            const int v = i / MM4;
            const int c = i - v * MM4;
            if (vg0 + v < n) {
                const int gchunk = (vg0 + v) * MM4 + c;
                f32x4 wv = __builtin_nontemporal_load(bw4g + gchunk);
                i32x4 iv = __builtin_nontemporal_load(bi4g + gchunk);
                const f32x4 cc = cs34g[c];
                wv.x *= cc.x; wv.y *= cc.y; wv.z *= cc.z; wv.w *= cc.w;
                s_bw4[v * SST + c] = wv;
                s_bi4[v * SST + c] = iv;
            }
        }
    }
    __syncthreads();

    f32x2 acc2[4];
    #pragma unroll
    for (int e = 0; e < 4; ++e) acc2[e] = (f32x2){0.f, 0.f};

    // ---- gather: 30 loads/lane as 5 batches x 6, depth-2 counted vmcnt(6) ----
    if (vg < n) {
        const int row   = vloc * SST;
        const int cbase = mc * 15;        // mc=0: chunks 0..14, mc=1: 15..29
        GB6 A, B, C;
        prep3(A, s_bw4, s_bi4, row, cbase + 0, jc, q, mbf);
        prep3(B, s_bw4, s_bi4, row, cbase + 3, jc, q, mbf);
        WAIT_VM6();
        consume6(acc2, A);
        prep3(C, s_bw4, s_bi4, row, cbase + 6, jc, q, mbf);
        WAIT_VM6();
        consume6(acc2, B);
        prep3(A, s_bw4, s_bi4, row, cbase + 9, jc, q, mbf);
        WAIT_VM6();
        consume6(acc2, C);
        prep3(B, s_bw4, s_bi4, row, cbase + 12, jc, q, mbf);
        WAIT_VM6();
        consume6(acc2, A);
        WAIT_VM0();
        consume6(acc2, B);
    }

    // ---- cross-lane reduce: jc (xor 4) then mc (xor 2) ----
    float a8[8] = { acc2[0].x, acc2[0].y, acc2[1].x, acc2[1].y,
                    acc2[2].x, acc2[2].y, acc2[3].x, acc2[3].y };
    #pragma unroll
    for (int e = 0; e < 8; ++e) a8[e] += __shfl_xor(a8[e], 4);
    #pragma unroll
    for (int e = 0; e < 8; ++e) a8[e] += __shfl_xor(a8[e], 2);

    if (jc == 0) {
        const f32x4 v = (mc == 0) ? (f32x4){a8[0], a8[1], a8[2], a8[3]}
                                  : (f32x4){a8[4], a8[5], a8[6], a8[7]};
        *(f32x4*)(&s_sig[vloc][q * 8 + mc * 4]) = v;
    }
    __syncthreads();   // s_sig ready; stream reads all done (s_buf reusable)

    // ---------------- Phase 2: fold (W @ s, relu, sum over t) ----------------
    // wave w (0..7) owns wave-uniform outputs [4w, 4w+4); lane = vertex (64).
    // Output pairs accumulated as f32x2 -> v_pk_fma_f32.
    {
        const int lane = tid & 63;
        const int wave = __builtin_amdgcn_readfirstlane(tid >> 6);  // 0..7

        float s[FEAT];
        #pragma unroll
        for (int f = 0; f < FEAT; ++f) s[f] = s_sig[lane][f];

        f32x2 oacc[2];
        oacc[0] = (f32x2){0.f, 0.f};
        oacc[1] = (f32x2){0.f, 0.f};
        const f32x2 zero2 = {0.f, 0.f};

        #pragma unroll 2
        for (int t = 0; t < NT; ++t) {
            #pragma unroll
            for (int op = 0; op < 2; ++op) {
                const int o0 = wave * 4 + op * 2;
                f32x2 pre = { bias[t * ODIM + o0], bias[t * ODIM + o0 + 1] };  // scalar
                const float* w0 = W + ((size_t)t * ODIM + o0) * FEAT;          // scalar
                const float* w1 = w0 + FEAT;
                #pragma unroll
                for (int f = 0; f < FEAT; ++f) {
                    const f32x2 wp = { w0[f], w1[f] };
                    const f32x2 sp = { s[f], s[f] };
                    pre = __builtin_elementwise_fma(wp, sp, pre);
                }
                oacc[op] += __builtin_elementwise_max(pre, zero2);
            }
        }

        *(f32x4*)(&s_out[lane][wave * 4]) =
            (f32x4){oacc[0].x, oacc[0].y, oacc[1].x, oacc[1].y};
    }
    __syncthreads();

    // ---------------- Phase 3: coalesced output write (normal stores) --------
    // 8 threads per vertex; each writes one float4 -> full 128B line/vertex.
    {
        const int v   = tid >> 3;
        const int oq  = tid & 7;
        const int vgo = vg0 + v;
        if (vgo < n) {
            const f32x4 val = { s_out[v][oq * 4 + 0], s_out[v][oq * 4 + 1],
                                s_out[v][oq * 4 + 2], s_out[v][oq * 4 + 3] };
            *(f32x4*)(out + (size_t)vgo * ODIM + oq * 4) = val;
        }
    }
}

extern "C" void kernel_launch(void* const* d_in, const int* in_sizes, int n_in,
                              void* d_out, int out_size, void* d_ws, size_t ws_size,
                              hipStream_t stream) {
    const float* mesh = (const float*)d_in[0];
    const float* bw   = (const float*)d_in[1];
    const float* ic   = (const float*)d_in[2];
    const float* W    = (const float*)d_in[3];
    const float* bias = (const float*)d_in[4];
    const int*   bi   = (const int*)d_in[5];
    float* out = (float*)d_out;

    const int n = in_sizes[0] / FEAT;   // N_VERTS
    const int total = n * FEAT;

    // workspace layout: [0,512) cs3, [512, 512 + n*16*2) bf16 mesh
    float* cs3 = (float*)d_ws;
    u16*   mbf = (u16*)((char*)d_ws + 512);

    const int cvt_blocks = (total / 8 + BLOCK - 1) / BLOCK;
    prep_kernel<<<cvt_blocks + 1, BLOCK, 0, stream>>>(mesh, ic, mbf, cs3, total);

    const int blocks = (n + VPB - 1) / VPB;
    conv_kernel<<<blocks, BLOCK, 0, stream>>>(mbf, bw, W, bias, bi, cs3, out, n);
}